// Round 3
// baseline (300.627 us; speedup 1.0000x reference)
//
#include <hip/hip_runtime.h>
#include <cstdint>

typedef _Float16 f16;
typedef __attribute__((ext_vector_type(4))) _Float16 f16x4;
typedef __attribute__((ext_vector_type(8))) _Float16 f16x8;
typedef __attribute__((ext_vector_type(4))) float f32x4;

#define DM   2048
#define TSEQ 2048
#define NB   2
#define NH   16
#define DKH  128
#define LOG2E 1.44269504088896f

__device__ __forceinline__ void gload_lds16(const void* g, void* l) {
  __builtin_amdgcn_global_load_lds((const __attribute__((address_space(1))) void*)g,
                                   (__attribute__((address_space(3))) void*)l, 16, 0, 0);
}

#define SBAR()   asm volatile("s_barrier" ::: "memory")
#define LGKM0()  { asm volatile("s_waitcnt lgkmcnt(0)" ::: "memory"); __builtin_amdgcn_sched_barrier(0); }
#define LGKM8()  asm volatile("s_waitcnt lgkmcnt(8)" ::: "memory")
#define VMCNT4() asm volatile("s_waitcnt vmcnt(4)" ::: "memory")

// ---------------- fp32 -> fp16 elementwise ----------------
__global__ __launch_bounds__(256) void cvt_kernel(const float* __restrict__ src,
                                                  f16* __restrict__ dst, int n8) {
  int i = blockIdx.x * 256 + threadIdx.x;
  if (i >= n8) return;
  const float4* s = (const float4*)src + 2 * (size_t)i;
  float4 a = s[0], b = s[1];
  f16x8 o;
  o[0]=(f16)a.x; o[1]=(f16)a.y; o[2]=(f16)a.z; o[3]=(f16)a.w;
  o[4]=(f16)b.x; o[5]=(f16)b.y; o[6]=(f16)b.z; o[7]=(f16)b.w;
  ((f16x8*)dst)[i] = o;
}

// ---------------- W [k][n] fp32 -> Wt [n][k] fp16 (transpose + convert) ----------------
__global__ __launch_bounds__(256) void wt_kernel(const float* __restrict__ W0, const float* __restrict__ W1,
                                                 const float* __restrict__ W2, const float* __restrict__ W3,
                                                 f16* __restrict__ Dqkv, f16* __restrict__ Dout) {
  __shared__ f16 S[64 * 80];
  int z = blockIdx.z;
  const float* W = (z == 0) ? W0 : (z == 1) ? W1 : (z == 2) ? W2 : W3;
  f16* D = (z < 3) ? (Dqkv + (size_t)z * DM * DM) : Dout;
  int n0 = blockIdx.x * 64, k0 = blockIdx.y * 64;
  int tid = threadIdx.x;
#pragma unroll
  for (int i = 0; i < 4; i++) {
    int flat = i * 256 + tid;          // 0..1023 -> 64 rows x 16 float4 cols
    int r = flat >> 4, c4 = flat & 15;
    float4 v = *(const float4*)(W + (size_t)(k0 + r) * DM + n0 + c4 * 4);
    S[(c4 * 4 + 0) * 80 + r] = (f16)v.x;
    S[(c4 * 4 + 1) * 80 + r] = (f16)v.y;
    S[(c4 * 4 + 2) * 80 + r] = (f16)v.z;
    S[(c4 * 4 + 3) * 80 + r] = (f16)v.w;
  }
  __syncthreads();
#pragma unroll
  for (int i = 0; i < 2; i++) {
    int flat = i * 256 + tid;          // 0..511 -> 64 n-rows x 8 chunks
    int nl = flat >> 3, kc = flat & 7;
    f16x8 v = *(const f16x8*)&S[nl * 80 + kc * 8];
    *(f16x8*)(D + (size_t)(n0 + nl) * DM + k0 + kc * 8) = v;
  }
}

// ---------------- GEMM, m201-geometry 8-phase counted-vmcnt (T1+T2+T3+T4+T5) --------
// BM=BN=256, BK=64. 512 threads = 8 waves (2M x 4N), wave owns 128x64 C.
// LDS: A dbuf 2x256x64 + B dbuf 2x256x64 = 128 KiB -> 1 block/CU (2 waves/SIMD).
// Iteration = 2 K-tiles; 8 phases; phase = one M-quadrant (2 frag rows) x 4 N x K=64
// = 16 MFMA. Stage slots (half-tile = 128 rows, 2 gload_lds/thread):
//   P0: b1.Ah0<-T1   P1: b1.Ah1<-T1 + b0.Bh0<-T0+2   P2: b0.Bh1<-T0+2
//   P4: b0.Ah0<-T0+2 P5: b0.Ah1<-T0+2 P6: b1.Bh0<-T1+2 P7: b1.Bh1<-T1+2
// vmcnt(4) ONLY at end of P3 (drains b1.B+b1.A for P4) and P7 (drains b0 for next P0);
// 2 pairs always stay in flight. Swizzle: 16B chunk c ^= (row&7), applied on the
// GLOBAL source (LDS dest linear, rule #21) and on the ds_read address. Verified
// conflict-free in round 2 (SQ_LDS_BANK_CONFLICT = 0).
template <int MODE>
__global__ __launch_bounds__(512, 2) void gemm_kernel(const f16* __restrict__ A, const f16* __restrict__ Bt,
                                                      const float* __restrict__ b0, const float* __restrict__ b1,
                                                      const float* __restrict__ b2,
                                                      f16* __restrict__ Oh, float* __restrict__ Of) {
  __shared__ __align__(16) f16 As[2][256 * 64];
  __shared__ __align__(16) f16 Bs[2][256 * 64];
  const int K = DM;
  const int NT = K / 64;           // 32 K-tiles
  const int NITER = NT / 2;        // 16 iterations
  constexpr int CPX = (MODE == 0) ? 48 : 16;   // blocks per XCD chunk (384/8, 128/8)
  int tid = threadIdx.x, l = tid & 63, w = tid >> 6;
  int lo = l & 15, hi = l >> 4;
  int wm = w >> 2, wn = w & 3;     // 2 x 4 wave grid
  int lin = blockIdx.x;
  int swz = (lin & 7) * CPX + (lin >> 3);      // bijective XCD swizzle (grid%8==0)
  int by = swz & 15, bx = swz >> 4;            // bx-contiguous per XCD: B panels L2-resident
  int m0 = by * 256, n0 = bx * 256;

  const f16* Ag = A + (size_t)m0 * K;
  const f16* Bg = Bt + (size_t)n0 * K;

  // stage half h (rows h*128..+127) of buffer b from K-tile t (2 gload_lds/thread)
  auto stageA = [&](int b, int h, int t) {
#pragma unroll
    for (int i = 0; i < 2; i++) {
      int flat = i * 512 + tid;            // 0..1023 -> 128 rows x 8 chunks
      int row = flat >> 3, c = flat & 7;
      int csw = c ^ (row & 7);             // pre-swizzled global source chunk
      gload_lds16(Ag + (size_t)(h * 128 + row) * K + t * 64 + csw * 8,
                  &As[b][h * 8192 + i * 4096 + w * 512]);
    }
  };
  auto stageB = [&](int b, int h, int t) {
#pragma unroll
    for (int i = 0; i < 2; i++) {
      int flat = i * 512 + tid;
      int row = flat >> 3, c = flat & 7;
      int csw = c ^ (row & 7);
      gload_lds16(Bg + (size_t)(h * 128 + row) * K + t * 64 + csw * 8,
                  &Bs[b][h * 8192 + i * 4096 + w * 512]);
    }
  };

  f32x4 acc[8][4] = {};
  f16x8 bfr[4][2];
  f16x8 af[2][2];

#define READ_BFRAGS(b)                                                              \
  {                                                                                 \
    _Pragma("unroll")                                                               \
    for (int ni = 0; ni < 4; ni++) {                                                \
      int row = wn * 64 + ni * 16 + lo;                                             \
      bfr[ni][0] = *(const f16x8*)&Bs[b][row * 64 + (((0 + hi) ^ (row & 7)) << 3)]; \
      bfr[ni][1] = *(const f16x8*)&Bs[b][row * 64 + (((4 + hi) ^ (row & 7)) << 3)]; \
    }                                                                               \
  }

#define READ_AFRAGS(b, q)                                                           \
  {                                                                                 \
    _Pragma("unroll")                                                               \
    for (int e = 0; e < 2; e++) {                                                   \
      int row = wm * 128 + ((q) * 2 + e) * 16 + lo;                                 \
      af[e][0] = *(const f16x8*)&As[b][row * 64 + (((0 + hi) ^ (row & 7)) << 3)];   \
      af[e][1] = *(const f16x8*)&As[b][row * 64 + (((4 + hi) ^ (row & 7)) << 3)];   \
    }                                                                               \
  }

#define MFMA_Q(q)                                                                   \
    __builtin_amdgcn_s_setprio(1);                                                  \
    _Pragma("unroll")                                                               \
    for (int e = 0; e < 2; e++)                                                     \
      _Pragma("unroll")                                                             \
      for (int ni = 0; ni < 4; ni++) {                                              \
        acc[(q)*2+e][ni] = __builtin_amdgcn_mfma_f32_16x16x32_f16(af[e][0], bfr[ni][0], acc[(q)*2+e][ni], 0, 0, 0); \
        acc[(q)*2+e][ni] = __builtin_amdgcn_mfma_f32_16x16x32_f16(af[e][1], bfr[ni][1], acc[(q)*2+e][ni], 0, 0, 0); \
      }                                                                             \
    __builtin_amdgcn_s_setprio(0);

  // prologue: b0 <- tile0 (complete), b1.B <- tile1; b1.A staged in-loop at P0/P1
  stageB(0, 0, 0); stageB(0, 1, 0);
  stageA(0, 0, 0); stageA(0, 1, 0);
  stageB(1, 0, 1); stageB(1, 1, 1);
  VMCNT4();                         // b0 landed; b1.B (2 pairs) in flight
  SBAR();

#pragma unroll 1
  for (int it = 0; it < NITER; ++it) {
    int T1 = 2 * it + 1;
    int t2 = (2 * it + 2 < NT) ? 2 * it + 2 : NT - 1;   // clamp keeps vmcnt uniform
    int t3 = (2 * it + 3 < NT) ? 2 * it + 3 : NT - 1;

    { // P0
      READ_BFRAGS(0); READ_AFRAGS(0, 0);
      stageA(1, 0, T1);
      LGKM8();
      SBAR(); LGKM0(); MFMA_Q(0); SBAR();
    }
    { // P1
      READ_AFRAGS(0, 1);
      stageA(1, 1, T1); stageB(0, 0, t2);
      SBAR(); LGKM0(); MFMA_Q(1); SBAR();
    }
    { // P2
      READ_AFRAGS(0, 2);
      stageB(0, 1, t2);
      SBAR(); LGKM0(); MFMA_Q(2); SBAR();
    }
    { // P3
      READ_AFRAGS(0, 3);
      SBAR(); LGKM0(); MFMA_Q(3);
      VMCNT4();                     // b1.B(T1)+b1.A(T1) drained; b0.B(t2) in flight
      SBAR();
    }
    { // P4
      READ_BFRAGS(1); READ_AFRAGS(1, 0);
      stageA(0, 0, t2);
      LGKM8();
      SBAR(); LGKM0(); MFMA_Q(0); SBAR();
    }
    { // P5
      READ_AFRAGS(1, 1);
      stageA(0, 1, t2);
      SBAR(); LGKM0(); MFMA_Q(1); SBAR();
    }
    { // P6
      READ_AFRAGS(1, 2);
      stageB(1, 0, t3);
      SBAR(); LGKM0(); MFMA_Q(2); SBAR();
    }
    { // P7
      READ_AFRAGS(1, 3);
      stageB(1, 1, t3);
      SBAR(); LGKM0(); MFMA_Q(3);
      VMCNT4();                     // b0(t2) drained; b1.B(t3) in flight
      SBAR();
    }
  }
  asm volatile("s_waitcnt vmcnt(0)" ::: "memory");  // drain tail prefetches

  // epilogue: C layout col = l&15, row = (l>>4)*4 + r
#pragma unroll
  for (int mi = 0; mi < 8; mi++) {
    int gm = m0 + wm * 128 + mi * 16 + (hi << 2);
#pragma unroll
    for (int ni = 0; ni < 4; ni++) {
      int gn = n0 + wn * 64 + ni * 16 + lo;
      if (MODE == 0) {
        int proj = gn >> 11, nn = gn & 2047;
        const float* bp = (proj == 0) ? b0 : (proj == 1) ? b1 : b2;
        float bias = bp[nn];
        int h = nn >> 7, d = nn & 127;
        int b = gm >> 11;
        int t0 = gm & 2047;
        if (proj < 2) {
#pragma unroll
          for (int r = 0; r < 4; r++) {
            Oh[(size_t)proj * ((size_t)NB * NH * TSEQ * DKH) +
               (((size_t)(b * NH + h) * TSEQ + t0 + r) * DKH) + d] = (f16)(acc[mi][ni][r] + bias);
          }
        } else {
          // V^T: [B,H,Dk,T] -- 4 consecutive t -> packed 8B store
          f16x4 pk;
#pragma unroll
          for (int r = 0; r < 4; r++) pk[r] = (f16)(acc[mi][ni][r] + bias);
          *(f16x4*)(Oh + 2ull * ((size_t)NB * NH * TSEQ * DKH) +
                    ((size_t)(b * NH + h) * DKH + d) * TSEQ + t0) = pk;
        }
      } else {
        float bias = b0[gn];
#pragma unroll
        for (int r = 0; r < 4; r++)
          Of[(size_t)(gm + r) * DM + gn] = acc[mi][ni][r] + bias;
      }
    }
  }
#undef READ_BFRAGS
#undef READ_AFRAGS
#undef MFMA_Q
}

// ---------------- flash attention v2 (swapped-QK^T, in-lane softmax) ----------------
__global__ __launch_bounds__(256, 2) void attn_kernel(const f16* __restrict__ Qb, const f16* __restrict__ Kb,
                                                      const f16* __restrict__ Vtb, f16* __restrict__ AO) {
  __shared__ f16 Ks[64 * 128];
  __shared__ f16 Vt[128 * 64];
  __shared__ f16 Ps[4][32 * 72];
  int tid = threadIdx.x, l = tid & 63, w = tid >> 6;
  int lo = l & 15, hi = l >> 4;
  int lin = blockIdx.x;
  int xcd = lin & 7, slot = lin >> 3;
  int bh = xcd * 4 + (slot & 3), qt = slot >> 2;   // bijective: 8 xcd * 4 bh * 16 qt
  const float CSC = 0.12753257f;   // (1/sqrt(128)) * log2(e)
  const float THR = 62.0f;         // raw-score defer threshold: p <= 2^(62*CSC) ~ 2^7.9
  const f16* Qg = Qb + (size_t)bh * TSEQ * DKH;
  const f16* Kg = Kb + (size_t)bh * TSEQ * DKH;
  const f16* Vg = Vtb + (size_t)bh * DKH * TSEQ;   // [Dk][T]

  // Q fragments in registers. As B-operand: col = lo = q-row, k(d) = c*32 + hi*8
  f16x8 aq[2][4];
#pragma unroll
  for (int hf = 0; hf < 2; hf++) {
    int qrow = qt * 128 + w * 32 + hf * 16 + lo;
#pragma unroll
    for (int c = 0; c < 4; c++)
      aq[hf][c] = *(const f16x8*)(Qg + (size_t)qrow * DKH + c * 32 + (hi << 3));
  }

  f32x4 o[2][8] = {};
  float mrow[2] = {-INFINITY, -INFINITY};
  float lrow[2] = {0.f, 0.f};

  for (int ktile = 0; ktile < TSEQ / 64; ++ktile) {
    __syncthreads();
    // stage K [64 kt][128 d]: 16 chunks/row, source chunk pre-swizzled by (row&15)
#pragma unroll
    for (int i = 0; i < 4; i++) {
      int chunk = (w * 4 + i) * 64 + l;
      int rowk = chunk >> 4, c = chunk & 15;
      int csw = c ^ (rowk & 15);
      gload_lds16(Kg + (size_t)(ktile * 64 + rowk) * DKH + csw * 8, &Ks[(w * 4 + i) * 512]);
    }
    // stage V^T [128 d][64 kt]: 8 chunks/row, source chunk pre-swizzled by (d&7)
#pragma unroll
    for (int i = 0; i < 4; i++) {
      int chunk = (w * 4 + i) * 64 + l;
      int d = chunk >> 3, c = chunk & 7;
      int csw = c ^ (d & 7);
      gload_lds16(Vg + (size_t)d * TSEQ + ktile * 64 + csw * 8, &Vt[(w * 4 + i) * 512]);
    }
    __syncthreads();

    // S^T = K Q^T: A = K rows (row=lo -> kt), B = Q (col=lo -> q).
    // Output: col = q = lo, row(reg r, hi) = kt = ks*16 + hi*4 + r.
    f32x4 s[2][4] = {};
    __builtin_amdgcn_s_setprio(1);
#pragma unroll
    for (int ks = 0; ks < 4; ++ks) {
      int ktl = ks * 16 + lo;
#pragma unroll
      for (int c = 0; c < 4; c++) {
        int cc = (c * 4 + hi) ^ lo;   // (ktl&15) == lo
        f16x8 bk = *(const f16x8*)&Ks[ktl * 128 + cc * 8];
        s[0][ks] = __builtin_amdgcn_mfma_f32_16x16x32_f16(bk, aq[0][c], s[0][ks], 0, 0, 0);
        s[1][ks] = __builtin_amdgcn_mfma_f32_16x16x32_f16(bk, aq[1][c], s[1][ks], 0, 0, 0);
      }
    }
    __builtin_amdgcn_s_setprio(0);

    // online softmax, reduction mostly in-lane (lane owns q-row = lo)
#pragma unroll
    for (int hf = 0; hf < 2; hf++) {
      float mk[4];
#pragma unroll
      for (int ks = 0; ks < 4; ks++)
        mk[ks] = fmaxf(fmaxf(s[hf][ks][0], s[hf][ks][1]), fmaxf(s[hf][ks][2], s[hf][ks][3]));
      float mt = fmaxf(fmaxf(mk[0], mk[1]), fmaxf(mk[2], mk[3]));
      mt = fmaxf(mt, __shfl_xor(mt, 16));
      mt = fmaxf(mt, __shfl_xor(mt, 32));   // row max, replicated across hi

      if (__any(mt > mrow[hf] + THR)) {     // wave-uniform; fires ~only on tile 0
        float mn = fmaxf(mrow[hf], mt);
        float al = exp2f((mrow[hf] - mn) * CSC);
        mrow[hf] = mn;
        lrow[hf] *= al;
        // redistribute al from lo-domain to o's (hi,r)-domain
        float alr[4];
#pragma unroll
        for (int r = 0; r < 4; r++) alr[r] = __shfl(al, (hi << 2) + r);
#pragma unroll
        for (int dsub = 0; dsub < 8; dsub++)
#pragma unroll
          for (int r = 0; r < 4; r++) o[hf][dsub][r] *= alr[r];
      }

      float mCn = -mrow[hf] * CSC;
      float sum = 0.f;
#pragma unroll
      for (int ks = 0; ks < 4; ks++) {
        f16x4 pk;
        float part = 0.f;
#pragma unroll
        for (int r = 0; r < 4; r++) {
          float p = exp2f(__builtin_fmaf(s[hf][ks][r], CSC, mCn));
          pk[r] = (f16)p;
          part += p;
        }
        sum += part;
        // P[q][kt]: row = hf*16+lo, col = ks*16 + hi*4 (+r packed) -> 8B store
        *(f16x4*)&Ps[w][(hf * 16 + lo) * 72 + ks * 16 + (hi << 2)] = pk;
      }
      sum += __shfl_xor(sum, 16);
      sum += __shfl_xor(sum, 32);
      lrow[hf] += sum;
    }

    // PV: o[hf][dsub] += P[16x64] * Vt^T[64 x dsub16]; each Vt read feeds 2 MFMAs
    f16x8 pa[2][2];
#pragma unroll
    for (int hf = 0; hf < 2; hf++)
#pragma unroll
      for (int kk = 0; kk < 2; kk++)
        pa[hf][kk] = *(const f16x8*)&Ps[w][(hf * 16 + lo) * 72 + kk * 32 + (hi << 3)];
    __builtin_amdgcn_s_setprio(1);
#pragma unroll
    for (int kk = 0; kk < 2; kk++) {
#pragma unroll
      for (int dsub = 0; dsub < 8; dsub++) {
        int d = dsub * 16 + lo;
        f16x8 vf = *(const f16x8*)&Vt[d * 64 + (((kk * 4 + hi) ^ (d & 7)) << 3)];
        o[0][dsub] = __builtin_amdgcn_mfma_f32_16x16x32_f16(pa[0][kk], vf, o[0][dsub], 0, 0, 0);
        o[1][dsub] = __builtin_amdgcn_mfma_f32_16x16x32_f16(pa[1][kk], vf, o[1][dsub], 0, 0, 0);
      }
    }
    __builtin_amdgcn_s_setprio(0);
  }

  // epilogue: AO[b][t][h*128 + d]; o row = q = hi*4+r, lrow lives in lo-domain
  int b = bh >> 4, h = bh & 15;
#pragma unroll
  for (int hf = 0; hf < 2; hf++) {
    float inv = 1.0f / lrow[hf];
    float invr[4];
#pragma unroll
    for (int r = 0; r < 4; r++) invr[r] = __shfl(inv, (hi << 2) + r);
#pragma unroll
    for (int r = 0; r < 4; r++) {
      int t = qt * 128 + w * 32 + hf * 16 + (hi << 2) + r;
      f16* dst = AO + ((size_t)b * TSEQ + t) * DM + h * DKH;
#pragma unroll
      for (int dsub = 0; dsub < 8; dsub++)
        dst[dsub * 16 + lo] = (f16)(o[hf][dsub][r] * invr[r]);
    }
  }
}

extern "C" void kernel_launch(void* const* d_in, const int* in_sizes, int n_in,
                              void* d_out, int out_size, void* d_ws, size_t ws_size,
                              hipStream_t stream) {
  const float* x  = (const float*)d_in[0];
  const float* Wq = (const float*)d_in[1];
  const float* bq = (const float*)d_in[2];
  const float* Wk = (const float*)d_in[3];
  const float* bk = (const float*)d_in[4];
  const float* Wv = (const float*)d_in[5];
  const float* bv = (const float*)d_in[6];
  const float* Wo = (const float*)d_in[7];
  const float* bo = (const float*)d_in[8];

  f16* ws    = (f16*)d_ws;
  f16* xb    = ws;                      //  8,388,608 elems  [reused as AO]
  f16* WtQKV = ws + 8388608ull;         // 12,582,912
  f16* WtO   = ws + 20971520ull;        //  4,194,304
  f16* Q     = ws + 25165824ull;        //  8,388,608
  f16* Kp    = ws + 33554432ull;        //  8,388,608
  f16* Vp    = ws + 41943040ull;        //  8,388,608  V^T [B,H,Dk,T]
  f16* AO    = xb;

  cvt_kernel<<<4096, 256, 0, stream>>>(x, xb, (NB * TSEQ * DM) / 8);
  wt_kernel<<<dim3(32, 32, 4), 256, 0, stream>>>(Wq, Wk, Wv, Wo, WtQKV, WtO);
  gemm_kernel<0><<<384, 512, 0, stream>>>(xb, WtQKV, bq, bk, bv, Q, nullptr);
  attn_kernel<<<512, 256, 0, stream>>>(Q, Kp, Vp, AO);
  gemm_kernel<1><<<128, 512, 0, stream>>>(AO, WtO, bo, nullptr, nullptr, nullptr, (float*)d_out);
}

// Round 4
// 266.479 us; speedup vs baseline: 1.1281x; 1.1281x over previous
//
#include <hip/hip_runtime.h>
#include <cstdint>

typedef _Float16 f16;
typedef __attribute__((ext_vector_type(4))) _Float16 f16x4;
typedef __attribute__((ext_vector_type(8))) _Float16 f16x8;
typedef __attribute__((ext_vector_type(4))) float f32x4;

#define DM   2048
#define TSEQ 2048
#define NB   2
#define NH   16
#define DKH  128
#define LOG2E 1.44269504088896f

__device__ __forceinline__ void gload_lds16(const void* g, void* l) {
  __builtin_amdgcn_global_load_lds((const __attribute__((address_space(1))) void*)g,
                                   (__attribute__((address_space(3))) void*)l, 16, 0, 0);
}

#define SBAR()  { asm volatile("s_barrier" ::: "memory"); __builtin_amdgcn_sched_barrier(0); }
#define LGKM0() { asm volatile("s_waitcnt lgkmcnt(0)" ::: "memory"); __builtin_amdgcn_sched_barrier(0); }

// ---------------- fp32 -> fp16 elementwise ----------------
__global__ __launch_bounds__(256) void cvt_kernel(const float* __restrict__ src,
                                                  f16* __restrict__ dst, int n8) {
  int i = blockIdx.x * 256 + threadIdx.x;
  if (i >= n8) return;
  const float4* s = (const float4*)src + 2 * (size_t)i;
  float4 a = s[0], b = s[1];
  f16x8 o;
  o[0]=(f16)a.x; o[1]=(f16)a.y; o[2]=(f16)a.z; o[3]=(f16)a.w;
  o[4]=(f16)b.x; o[5]=(f16)b.y; o[6]=(f16)b.z; o[7]=(f16)b.w;
  ((f16x8*)dst)[i] = o;
}

// ---------------- W [k][n] fp32 -> Wt [n][k] fp16 (transpose + convert) ----------------
__global__ __launch_bounds__(256) void wt_kernel(const float* __restrict__ W0, const float* __restrict__ W1,
                                                 const float* __restrict__ W2, const float* __restrict__ W3,
                                                 f16* __restrict__ Dqkv, f16* __restrict__ Dout) {
  __shared__ f16 S[64 * 80];
  int z = blockIdx.z;
  const float* W = (z == 0) ? W0 : (z == 1) ? W1 : (z == 2) ? W2 : W3;
  f16* D = (z < 3) ? (Dqkv + (size_t)z * DM * DM) : Dout;
  int n0 = blockIdx.x * 64, k0 = blockIdx.y * 64;
  int tid = threadIdx.x;
#pragma unroll
  for (int i = 0; i < 4; i++) {
    int flat = i * 256 + tid;          // 0..1023 -> 64 rows x 16 float4 cols
    int r = flat >> 4, c4 = flat & 15;
    float4 v = *(const float4*)(W + (size_t)(k0 + r) * DM + n0 + c4 * 4);
    S[(c4 * 4 + 0) * 80 + r] = (f16)v.x;
    S[(c4 * 4 + 1) * 80 + r] = (f16)v.y;
    S[(c4 * 4 + 2) * 80 + r] = (f16)v.z;
    S[(c4 * 4 + 3) * 80 + r] = (f16)v.w;
  }
  __syncthreads();
#pragma unroll
  for (int i = 0; i < 2; i++) {
    int flat = i * 256 + tid;          // 0..511 -> 64 n-rows x 8 chunks
    int nl = flat >> 3, kc = flat & 7;
    f16x8 v = *(const f16x8*)&S[nl * 80 + kc * 8];
    *(f16x8*)(D + (size_t)(n0 + nl) * DM + k0 + kc * 8) = v;
  }
}

// ---------------- GEMM, 8-phase early-read counted-vmcnt (T1+T2+T3+T4+T5) -----------
// MODE 0: BM=256 BN=192, grid 16x32=512 -> 2 CLEAN rounds at 1 block/CU.
// MODE 1: BM=256 BN=128, grid 16x16=256 -> 1 clean round.
// 512 threads = 8 waves (2M x 4N), wave owns 128 x (BN/4).
// K-tile (BK=64) = 4 MFMA phases (M-quadrants). ALL frag reads for the K-tile
// (2*NFR bfr + 16 af ds_read_b128) issue at phase 0; compiler's fine-grained
// lgkmcnt lets Q0 start after the first reads while af1-3 land under Q0's MFMAs.
// Phases 1-3 are near-pure MFMA. lgkmcnt(0) at end of P1 + barrier makes stages
// into the live buffer formally safe at P2 (A units) / P3 (B units).
// Staging: 64-row units (1 gload_lds/thread/unit); tile t+2 -> buf0 at P2/P3,
// t+3 -> buf1 at P6/P7; vmcnt(UPT=4+NFR) ONLY at tile boundaries (prefetch
// distance 5-6 phases >> HBM latency). Swizzle: 16B chunk c ^= (row&7) applied
// on the GLOBAL source (LDS dest linear) and on ds_read addr (verified: 0 conflicts).
template <int MODE>
__global__ __launch_bounds__(512, 2) void gemm_kernel(const f16* __restrict__ A, const f16* __restrict__ Bt,
                                                      const float* __restrict__ b0, const float* __restrict__ b1,
                                                      const float* __restrict__ b2,
                                                      f16* __restrict__ Oh, float* __restrict__ Of) {
  constexpr int BN   = (MODE == 0) ? 192 : 128;
  constexpr int NFR  = BN / 64;            // N frags per wave: 3 / 2
  constexpr int WN   = BN / 4;             // wave N extent: 48 / 32
  constexpr int NXB  = (MODE == 0) ? 32 : 16;  // 6144/192, 2048/128
  constexpr int CPX  = (16 * NXB) / 8;     // blocks per XCD chunk: 64 / 32
  __shared__ __align__(16) f16 As[2][256 * 64];
  __shared__ __align__(16) f16 Bs[2][NFR * 64 * 64];
  const int K = DM;
  const int NT = K / 64;                   // 32 K-tiles
  const int NITER = NT / 2;                // 16 iterations
  int tid = threadIdx.x, l = tid & 63, w = tid >> 6;
  int lo = l & 15, hi = l >> 4;
  int wm = w >> 2, wn = w & 3;             // 2 x 4 wave grid
  int lin = blockIdx.x;
  int swz = (lin & 7) * CPX + (lin >> 3);  // bijective XCD swizzle (grid%8==0)
  int by = swz & 15, bx = swz >> 4;        // bx-contiguous per XCD -> B panels L2-resident
  int m0 = by * 256, n0 = bx * BN;

  const f16* Ag = A + (size_t)m0 * K;
  const f16* Bg = Bt + (size_t)n0 * K;

  // stage one 64-row unit (1 gload_lds per thread; wave w covers rows u*64+w*8..+7)
  auto stageAu = [&](int b, int u, int t) {
    int rin = (w << 3) + (l >> 3);               // 0..63 within unit
    int csw = (l & 7) ^ (rin & 7);               // pre-swizzled global source chunk
    gload_lds16(Ag + (size_t)(u * 64 + rin) * K + t * 64 + csw * 8,
                &As[b][u * 4096 + w * 512]);
  };
  auto stageBu = [&](int b, int u, int t) {
    int rin = (w << 3) + (l >> 3);
    int csw = (l & 7) ^ (rin & 7);
    gload_lds16(Bg + (size_t)(u * 64 + rin) * K + t * 64 + csw * 8,
                &Bs[b][u * 4096 + w * 512]);
  };

  f32x4 acc[8][NFR] = {};
  f16x8 bfr[NFR][2];
  f16x8 af[4][2][2];

#define READ_BFRAGS(b)                                                              \
  {                                                                                 \
    _Pragma("unroll")                                                               \
    for (int ni = 0; ni < NFR; ni++) {                                              \
      int row = wn * WN + ni * 16 + lo;                                             \
      bfr[ni][0] = *(const f16x8*)&Bs[b][row * 64 + (((0 + hi) ^ (row & 7)) << 3)]; \
      bfr[ni][1] = *(const f16x8*)&Bs[b][row * 64 + (((4 + hi) ^ (row & 7)) << 3)]; \
    }                                                                               \
  }

#define READ_AFRAGS_ALL(b)                                                          \
  {                                                                                 \
    _Pragma("unroll")                                                               \
    for (int q = 0; q < 4; q++)                                                     \
      _Pragma("unroll")                                                             \
      for (int e = 0; e < 2; e++) {                                                 \
        int row = wm * 128 + (q * 2 + e) * 16 + lo;                                 \
        af[q][e][0] = *(const f16x8*)&As[b][row * 64 + (((0 + hi) ^ (row & 7)) << 3)]; \
        af[q][e][1] = *(const f16x8*)&As[b][row * 64 + (((4 + hi) ^ (row & 7)) << 3)]; \
      }                                                                             \
  }

#define MFMA_Q(q)                                                                   \
    __builtin_amdgcn_s_setprio(1);                                                  \
    _Pragma("unroll")                                                               \
    for (int e = 0; e < 2; e++)                                                     \
      _Pragma("unroll")                                                             \
      for (int ni = 0; ni < NFR; ni++) {                                            \
        acc[(q)*2+e][ni] = __builtin_amdgcn_mfma_f32_16x16x32_f16(af[q][e][0], bfr[ni][0], acc[(q)*2+e][ni], 0, 0, 0); \
        acc[(q)*2+e][ni] = __builtin_amdgcn_mfma_f32_16x16x32_f16(af[q][e][1], bfr[ni][1], acc[(q)*2+e][ni], 0, 0, 0); \
      }                                                                             \
    __builtin_amdgcn_s_setprio(0);

#define VMCNT_UPT()                                                                 \
    if constexpr (MODE == 0) { asm volatile("s_waitcnt vmcnt(7)" ::: "memory"); }   \
    else                     { asm volatile("s_waitcnt vmcnt(6)" ::: "memory"); }   \
    __builtin_amdgcn_sched_barrier(0);

  // prologue: T0 -> buf0, T1 -> buf1 (UPT units each); drain T0, keep T1 flying
#pragma unroll
  for (int u = 0; u < 4; u++) stageAu(0, u, 0);
#pragma unroll
  for (int u = 0; u < NFR; u++) stageBu(0, u, 0);
#pragma unroll
  for (int u = 0; u < 4; u++) stageAu(1, u, 1);
#pragma unroll
  for (int u = 0; u < NFR; u++) stageBu(1, u, 1);
  VMCNT_UPT();
  SBAR();

#pragma unroll 1
  for (int it = 0; it < NITER; ++it) {
    int t2 = (2 * it + 2 < NT) ? 2 * it + 2 : NT - 1;   // clamp keeps vmcnt uniform
    int t3 = (2 * it + 3 < NT) ? 2 * it + 3 : NT - 1;

    // ---- K-tile A: compute buf0, stage t2 -> buf0 ----
    { // P0: full read burst + Q0 (compiler inserts fine-grained lgkmcnt before Q0)
      READ_BFRAGS(0); READ_AFRAGS_ALL(0);
      MFMA_Q(0);
      SBAR();
    }
    { // P1: Q1; then lgkm(0) so ALL reads of buf0 are done before P1's barrier
      MFMA_Q(1);
      LGKM0();
      SBAR();
    }
    { // P2: stage A units (safe: every wave passed P1 with reads complete)
#pragma unroll
      for (int u = 0; u < 4; u++) stageAu(0, u, t2);
      MFMA_Q(2);
      SBAR();
    }
    { // P3: stage B units; tile-boundary drain (leaves t2's UPT units in flight)
#pragma unroll
      for (int u = 0; u < NFR; u++) stageBu(0, u, t2);
      MFMA_Q(3);
      VMCNT_UPT();
      SBAR();
    }

    // ---- K-tile B: compute buf1, stage t3 -> buf1 ----
    { // P4
      READ_BFRAGS(1); READ_AFRAGS_ALL(1);
      MFMA_Q(0);
      SBAR();
    }
    { // P5
      MFMA_Q(1);
      LGKM0();
      SBAR();
    }
    { // P6
#pragma unroll
      for (int u = 0; u < 4; u++) stageAu(1, u, t3);
      MFMA_Q(2);
      SBAR();
    }
    { // P7
#pragma unroll
      for (int u = 0; u < NFR; u++) stageBu(1, u, t3);
      MFMA_Q(3);
      VMCNT_UPT();
      SBAR();
    }
  }
  asm volatile("s_waitcnt vmcnt(0)" ::: "memory");  // drain tail prefetches

  // epilogue: C layout col = l&15, row = (l>>4)*4 + r
#pragma unroll
  for (int mi = 0; mi < 8; mi++) {
    int gm = m0 + wm * 128 + mi * 16 + (hi << 2);
#pragma unroll
    for (int ni = 0; ni < NFR; ni++) {
      int gn = n0 + wn * WN + ni * 16 + lo;
      if (MODE == 0) {
        int proj = gn >> 11, nn = gn & 2047;
        const float* bp = (proj == 0) ? b0 : (proj == 1) ? b1 : b2;
        float bias = bp[nn];
        int h = nn >> 7, d = nn & 127;
        int b = gm >> 11;
        int t0 = gm & 2047;
        if (proj < 2) {
#pragma unroll
          for (int r = 0; r < 4; r++) {
            Oh[(size_t)proj * ((size_t)NB * NH * TSEQ * DKH) +
               (((size_t)(b * NH + h) * TSEQ + t0 + r) * DKH) + d] = (f16)(acc[mi][ni][r] + bias);
          }
        } else {
          // V^T: [B,H,Dk,T] -- 4 consecutive t -> packed 8B store
          f16x4 pk;
#pragma unroll
          for (int r = 0; r < 4; r++) pk[r] = (f16)(acc[mi][ni][r] + bias);
          *(f16x4*)(Oh + 2ull * ((size_t)NB * NH * TSEQ * DKH) +
                    ((size_t)(b * NH + h) * DKH + d) * TSEQ + t0) = pk;
        }
      } else {
        float bias = b0[gn];
#pragma unroll
        for (int r = 0; r < 4; r++)
          Of[(size_t)(gm + r) * DM + gn] = acc[mi][ni][r] + bias;
      }
    }
  }
#undef READ_BFRAGS
#undef READ_AFRAGS_ALL
#undef MFMA_Q
#undef VMCNT_UPT
}

// ---------------- flash attention v2 (swapped-QK^T, in-lane softmax) ----------------
__global__ __launch_bounds__(256, 2) void attn_kernel(const f16* __restrict__ Qb, const f16* __restrict__ Kb,
                                                      const f16* __restrict__ Vtb, f16* __restrict__ AO) {
  __shared__ f16 Ks[64 * 128];
  __shared__ f16 Vt[128 * 64];
  __shared__ f16 Ps[4][32 * 72];
  int tid = threadIdx.x, l = tid & 63, w = tid >> 6;
  int lo = l & 15, hi = l >> 4;
  int lin = blockIdx.x;
  int xcd = lin & 7, slot = lin >> 3;
  int bh = xcd * 4 + (slot & 3), qt = slot >> 2;   // bijective: 8 xcd * 4 bh * 16 qt
  const float CSC = 0.12753257f;   // (1/sqrt(128)) * log2(e)
  const float THR = 62.0f;         // raw-score defer threshold: p <= 2^(62*CSC) ~ 2^7.9
  const f16* Qg = Qb + (size_t)bh * TSEQ * DKH;
  const f16* Kg = Kb + (size_t)bh * TSEQ * DKH;
  const f16* Vg = Vtb + (size_t)bh * DKH * TSEQ;   // [Dk][T]

  // Q fragments in registers. As B-operand: col = lo = q-row, k(d) = c*32 + hi*8
  f16x8 aq[2][4];
#pragma unroll
  for (int hf = 0; hf < 2; hf++) {
    int qrow = qt * 128 + w * 32 + hf * 16 + lo;
#pragma unroll
    for (int c = 0; c < 4; c++)
      aq[hf][c] = *(const f16x8*)(Qg + (size_t)qrow * DKH + c * 32 + (hi << 3));
  }

  f32x4 o[2][8] = {};
  float mrow[2] = {-INFINITY, -INFINITY};
  float lrow[2] = {0.f, 0.f};

  for (int ktile = 0; ktile < TSEQ / 64; ++ktile) {
    __syncthreads();
    // stage K [64 kt][128 d]: 16 chunks/row, source chunk pre-swizzled by (row&15)
#pragma unroll
    for (int i = 0; i < 4; i++) {
      int chunk = (w * 4 + i) * 64 + l;
      int rowk = chunk >> 4, c = chunk & 15;
      int csw = c ^ (rowk & 15);
      gload_lds16(Kg + (size_t)(ktile * 64 + rowk) * DKH + csw * 8, &Ks[(w * 4 + i) * 512]);
    }
    // stage V^T [128 d][64 kt]: 8 chunks/row, source chunk pre-swizzled by (d&7)
#pragma unroll
    for (int i = 0; i < 4; i++) {
      int chunk = (w * 4 + i) * 64 + l;
      int d = chunk >> 3, c = chunk & 7;
      int csw = c ^ (d & 7);
      gload_lds16(Vg + (size_t)d * TSEQ + ktile * 64 + csw * 8, &Vt[(w * 4 + i) * 512]);
    }
    __syncthreads();

    // S^T = K Q^T: A = K rows (row=lo -> kt), B = Q (col=lo -> q).
    // Output: col = q = lo, row(reg r, hi) = kt = ks*16 + hi*4 + r.
    f32x4 s[2][4] = {};
    __builtin_amdgcn_s_setprio(1);
#pragma unroll
    for (int ks = 0; ks < 4; ++ks) {
      int ktl = ks * 16 + lo;
#pragma unroll
      for (int c = 0; c < 4; c++) {
        int cc = (c * 4 + hi) ^ lo;   // (ktl&15) == lo
        f16x8 bk = *(const f16x8*)&Ks[ktl * 128 + cc * 8];
        s[0][ks] = __builtin_amdgcn_mfma_f32_16x16x32_f16(bk, aq[0][c], s[0][ks], 0, 0, 0);
        s[1][ks] = __builtin_amdgcn_mfma_f32_16x16x32_f16(bk, aq[1][c], s[1][ks], 0, 0, 0);
      }
    }
    __builtin_amdgcn_s_setprio(0);

    // online softmax, reduction mostly in-lane (lane owns q-row = lo)
#pragma unroll
    for (int hf = 0; hf < 2; hf++) {
      float mk[4];
#pragma unroll
      for (int ks = 0; ks < 4; ks++)
        mk[ks] = fmaxf(fmaxf(s[hf][ks][0], s[hf][ks][1]), fmaxf(s[hf][ks][2], s[hf][ks][3]));
      float mt = fmaxf(fmaxf(mk[0], mk[1]), fmaxf(mk[2], mk[3]));
      mt = fmaxf(mt, __shfl_xor(mt, 16));
      mt = fmaxf(mt, __shfl_xor(mt, 32));   // row max, replicated across hi

      if (__any(mt > mrow[hf] + THR)) {     // wave-uniform; fires ~only on tile 0
        float mn = fmaxf(mrow[hf], mt);
        float al = exp2f((mrow[hf] - mn) * CSC);
        mrow[hf] = mn;
        lrow[hf] *= al;
        // redistribute al from lo-domain to o's (hi,r)-domain
        float alr[4];
#pragma unroll
        for (int r = 0; r < 4; r++) alr[r] = __shfl(al, (hi << 2) + r);
#pragma unroll
        for (int dsub = 0; dsub < 8; dsub++)
#pragma unroll
          for (int r = 0; r < 4; r++) o[hf][dsub][r] *= alr[r];
      }

      float mCn = -mrow[hf] * CSC;
      float sum = 0.f;
#pragma unroll
      for (int ks = 0; ks < 4; ks++) {
        f16x4 pk;
        float part = 0.f;
#pragma unroll
        for (int r = 0; r < 4; r++) {
          float p = exp2f(__builtin_fmaf(s[hf][ks][r], CSC, mCn));
          pk[r] = (f16)p;
          part += p;
        }
        sum += part;
        // P[q][kt]: row = hf*16+lo, col = ks*16 + hi*4 (+r packed) -> 8B store
        *(f16x4*)&Ps[w][(hf * 16 + lo) * 72 + ks * 16 + (hi << 2)] = pk;
      }
      sum += __shfl_xor(sum, 16);
      sum += __shfl_xor(sum, 32);
      lrow[hf] += sum;
    }

    // PV: o[hf][dsub] += P[16x64] * Vt^T[64 x dsub16]; each Vt read feeds 2 MFMAs
    f16x8 pa[2][2];
#pragma unroll
    for (int hf = 0; hf < 2; hf++)
#pragma unroll
      for (int kk = 0; kk < 2; kk++)
        pa[hf][kk] = *(const f16x8*)&Ps[w][(hf * 16 + lo) * 72 + kk * 32 + (hi << 3)];
    __builtin_amdgcn_s_setprio(1);
#pragma unroll
    for (int kk = 0; kk < 2; kk++) {
#pragma unroll
      for (int dsub = 0; dsub < 8; dsub++) {
        int d = dsub * 16 + lo;
        f16x8 vf = *(const f16x8*)&Vt[d * 64 + (((kk * 4 + hi) ^ (d & 7)) << 3)];
        o[0][dsub] = __builtin_amdgcn_mfma_f32_16x16x32_f16(pa[0][kk], vf, o[0][dsub], 0, 0, 0);
        o[1][dsub] = __builtin_amdgcn_mfma_f32_16x16x32_f16(pa[1][kk], vf, o[1][dsub], 0, 0, 0);
      }
    }
    __builtin_amdgcn_s_setprio(0);
  }

  // epilogue: AO[b][t][h*128 + d]; o row = q = hi*4+r, lrow lives in lo-domain
  int b = bh >> 4, h = bh & 15;
#pragma unroll
  for (int hf = 0; hf < 2; hf++) {
    float inv = 1.0f / lrow[hf];
    float invr[4];
#pragma unroll
    for (int r = 0; r < 4; r++) invr[r] = __shfl(inv, (hi << 2) + r);
#pragma unroll
    for (int r = 0; r < 4; r++) {
      int t = qt * 128 + w * 32 + hf * 16 + (hi << 2) + r;
      f16* dst = AO + ((size_t)b * TSEQ + t) * DM + h * DKH;
#pragma unroll
      for (int dsub = 0; dsub < 8; dsub++)
        dst[dsub * 16 + lo] = (f16)(o[hf][dsub][r] * invr[r]);
    }
  }
}

extern "C" void kernel_launch(void* const* d_in, const int* in_sizes, int n_in,
                              void* d_out, int out_size, void* d_ws, size_t ws_size,
                              hipStream_t stream) {
  const float* x  = (const float*)d_in[0];
  const float* Wq = (const float*)d_in[1];
  const float* bq = (const float*)d_in[2];
  const float* Wk = (const float*)d_in[3];
  const float* bk = (const float*)d_in[4];
  const float* Wv = (const float*)d_in[5];
  const float* bv = (const float*)d_in[6];
  const float* Wo = (const float*)d_in[7];
  const float* bo = (const float*)d_in[8];

  f16* ws    = (f16*)d_ws;
  f16* xb    = ws;                      //  8,388,608 elems  [reused as AO]
  f16* WtQKV = ws + 8388608ull;         // 12,582,912
  f16* WtO   = ws + 20971520ull;        //  4,194,304
  f16* Q     = ws + 25165824ull;        //  8,388,608
  f16* Kp    = ws + 33554432ull;        //  8,388,608
  f16* Vp    = ws + 41943040ull;        //  8,388,608  V^T [B,H,Dk,T]
  f16* AO    = xb;

  cvt_kernel<<<4096, 256, 0, stream>>>(x, xb, (NB * TSEQ * DM) / 8);
  wt_kernel<<<dim3(32, 32, 4), 256, 0, stream>>>(Wq, Wk, Wv, Wo, WtQKV, WtO);
  gemm_kernel<0><<<512, 512, 0, stream>>>(xb, WtQKV, bq, bk, bv, Q, nullptr);
  attn_kernel<<<512, 256, 0, stream>>>(Q, Kp, Vp, AO);
  gemm_kernel<1><<<256, 512, 0, stream>>>(AO, WtO, bo, nullptr, nullptr, nullptr, (float*)d_out);
}

// Round 5
// 261.896 us; speedup vs baseline: 1.1479x; 1.0175x over previous
//
#include <hip/hip_runtime.h>
#include <cstdint>

typedef _Float16 f16;
typedef __attribute__((ext_vector_type(4))) _Float16 f16x4;
typedef __attribute__((ext_vector_type(8))) _Float16 f16x8;
typedef __attribute__((ext_vector_type(4))) float f32x4;

#define DM   2048
#define TSEQ 2048
#define NB   2
#define NH   16
#define DKH  128
#define LOG2E 1.44269504088896f

__device__ __forceinline__ void gload_lds16(const void* g, void* l) {
  __builtin_amdgcn_global_load_lds((const __attribute__((address_space(1))) void*)g,
                                   (__attribute__((address_space(3))) void*)l, 16, 0, 0);
}

#define SBAR()  { asm volatile("s_barrier" ::: "memory"); __builtin_amdgcn_sched_barrier(0); }
#define LGKM0() { asm volatile("s_waitcnt lgkmcnt(0)" ::: "memory"); __builtin_amdgcn_sched_barrier(0); }
#define VMCNT0() { asm volatile("s_waitcnt vmcnt(0)" ::: "memory"); __builtin_amdgcn_sched_barrier(0); }

// ---------------- fp32 -> fp16 elementwise ----------------
__global__ __launch_bounds__(256) void cvt_kernel(const float* __restrict__ src,
                                                  f16* __restrict__ dst, int n8) {
  int i = blockIdx.x * 256 + threadIdx.x;
  if (i >= n8) return;
  const float4* s = (const float4*)src + 2 * (size_t)i;
  float4 a = s[0], b = s[1];
  f16x8 o;
  o[0]=(f16)a.x; o[1]=(f16)a.y; o[2]=(f16)a.z; o[3]=(f16)a.w;
  o[4]=(f16)b.x; o[5]=(f16)b.y; o[6]=(f16)b.z; o[7]=(f16)b.w;
  ((f16x8*)dst)[i] = o;
}

// ---------------- W [k][n] fp32 -> Wt [n][k] fp16 (transpose + convert) ----------------
__global__ __launch_bounds__(256) void wt_kernel(const float* __restrict__ W0, const float* __restrict__ W1,
                                                 const float* __restrict__ W2, const float* __restrict__ W3,
                                                 f16* __restrict__ Dqkv, f16* __restrict__ Dout) {
  __shared__ f16 S[64 * 80];
  int z = blockIdx.z;
  const float* W = (z == 0) ? W0 : (z == 1) ? W1 : (z == 2) ? W2 : W3;
  f16* D = (z < 3) ? (Dqkv + (size_t)z * DM * DM) : Dout;
  int n0 = blockIdx.x * 64, k0 = blockIdx.y * 64;
  int tid = threadIdx.x;
#pragma unroll
  for (int i = 0; i < 4; i++) {
    int flat = i * 256 + tid;          // 0..1023 -> 64 rows x 16 float4 cols
    int r = flat >> 4, c4 = flat & 15;
    float4 v = *(const float4*)(W + (size_t)(k0 + r) * DM + n0 + c4 * 4);
    S[(c4 * 4 + 0) * 80 + r] = (f16)v.x;
    S[(c4 * 4 + 1) * 80 + r] = (f16)v.y;
    S[(c4 * 4 + 2) * 80 + r] = (f16)v.z;
    S[(c4 * 4 + 3) * 80 + r] = (f16)v.w;
  }
  __syncthreads();
#pragma unroll
  for (int i = 0; i < 2; i++) {
    int flat = i * 256 + tid;          // 0..511 -> 64 n-rows x 8 chunks
    int nl = flat >> 3, kc = flat & 7;
    f16x8 v = *(const f16x8*)&S[nl * 80 + kc * 8];
    *(f16x8*)(D + (size_t)(n0 + nl) * DM + k0 + kc * 8) = v;
  }
}

// ---------------- GEMM, "flow" schedule: reads overlap MFMA, 2 barriers/iter --------
// MODE 0: BM=256 BN=192, grid 16x32=512 -> 2 clean rounds at 1 block/CU.
// MODE 1: BM=256 BN=128, grid 16x16=256 -> 1 clean round.
// 512 threads = 8 waves (2M x 4N), wave owns 128 x (BN/4). BK=64, 4 MFMA phases/tile.
// Per phase q: MFMA_Q(q) then issue af[q+1] ds_reads -> value deps give counted
// lgkmcnt; reads complete under the NEXT phase's MFMA. Only ONE barrier per tile:
//   lgkmcnt(0)  -- this wave's reads of cur buf all complete (operands in regs)
//   vmcnt(0)    -- this wave's stage of the OTHER buf (issued 1 tile ago) landed
//   s_barrier   -- now ALL waves' reads done + other-buf data visible
//   stage t+2 -> cur buf (legal: every wave past lgkm0); MFMA q3 (reg operands);
//   sched_barrier(0); reload bfr/af0 from other buf (pinned after last bfr use).
// Prefetch distance = 4 phases (~2500 cyc) >> HBM latency; vmcnt(0) drains exactly
// the 7(6) unit-loads issued one tile earlier (nothing else in flight) == counted.
// Swizzle: 16B chunk c ^= (row&7) on GLOBAL source (LDS dest linear) and on ds_read
// addr -- verified 0 bank conflicts in rounds 2-4.
template <int MODE>
__global__ __launch_bounds__(512, 2) void gemm_kernel(const f16* __restrict__ A, const f16* __restrict__ Bt,
                                                      const float* __restrict__ b0, const float* __restrict__ b1,
                                                      const float* __restrict__ b2,
                                                      f16* __restrict__ Oh, float* __restrict__ Of) {
  constexpr int BN   = (MODE == 0) ? 192 : 128;
  constexpr int NFR  = BN / 64;            // B frags per wave: 3 / 2
  constexpr int WN   = BN / 4;             // wave N extent: 48 / 32
  constexpr int NXB  = (MODE == 0) ? 32 : 16;  // 6144/192, 2048/128
  constexpr int CPX  = (16 * NXB) / 8;     // blocks per XCD chunk: 64 / 32
  constexpr int UNITS = 4 + NFR;           // 64-row stage units per tile: 7 / 6
  __shared__ __align__(16) f16 As[2][256 * 64];
  __shared__ __align__(16) f16 Bs[2][NFR * 64 * 64];
  const int K = DM;
  const int NT = K / 64;                   // 32 K-tiles
  const int NITER = NT / 2;                // 16 iterations
  int tid = threadIdx.x, l = tid & 63, w = tid >> 6;
  int lo = l & 15, hi = l >> 4;
  int wm = w >> 2, wn = w & 3;             // 2 x 4 wave grid
  int lin = blockIdx.x;
  int swz = (lin & 7) * CPX + (lin >> 3);  // bijective XCD swizzle (grid%8==0)
  int by = swz & 15, bx = swz >> 4;        // bx-contiguous per XCD -> B panels L2-resident
  int m0 = by * 256, n0 = bx * BN;

  const f16* Ag = A + (size_t)m0 * K;
  const f16* Bg = Bt + (size_t)n0 * K;

  // stage one 64-row unit (1 gload_lds per thread; wave w covers rows u*64+w*8..+7)
  auto stageAu = [&](int b, int u, int t) {
    int rin = (w << 3) + (l >> 3);               // 0..63 within unit
    int csw = (l & 7) ^ (rin & 7);               // pre-swizzled global source chunk
    gload_lds16(Ag + (size_t)(u * 64 + rin) * K + t * 64 + csw * 8,
                &As[b][u * 4096 + w * 512]);
  };
  auto stageBu = [&](int b, int u, int t) {
    int rin = (w << 3) + (l >> 3);
    int csw = (l & 7) ^ (rin & 7);
    gload_lds16(Bg + (size_t)(u * 64 + rin) * K + t * 64 + csw * 8,
                &Bs[b][u * 4096 + w * 512]);
  };
  auto stageAll = [&](int b, int t) {
#pragma unroll
    for (int u = 0; u < 4; u++) stageAu(b, u, t);
#pragma unroll
    for (int u = 0; u < NFR; u++) stageBu(b, u, t);
  };

  f32x4 acc[8][NFR] = {};
  f16x8 bfr[NFR][2];
  f16x8 af[4][2][2];   // [quadrant][e][khalf] -- all quadrants live (rotating reads)

#define READ_BFR(b)                                                                 \
  {                                                                                 \
    _Pragma("unroll")                                                               \
    for (int ni = 0; ni < NFR; ni++) {                                              \
      int row = wn * WN + ni * 16 + lo;                                             \
      bfr[ni][0] = *(const f16x8*)&Bs[b][row * 64 + (((0 + hi) ^ (row & 7)) << 3)]; \
      bfr[ni][1] = *(const f16x8*)&Bs[b][row * 64 + (((4 + hi) ^ (row & 7)) << 3)]; \
    }                                                                               \
  }

#define READ_AF(b, q)                                                               \
  {                                                                                 \
    _Pragma("unroll")                                                               \
    for (int e = 0; e < 2; e++) {                                                   \
      int row = wm * 128 + ((q) * 2 + e) * 16 + lo;                                 \
      af[q][e][0] = *(const f16x8*)&As[b][row * 64 + (((0 + hi) ^ (row & 7)) << 3)]; \
      af[q][e][1] = *(const f16x8*)&As[b][row * 64 + (((4 + hi) ^ (row & 7)) << 3)]; \
    }                                                                               \
  }

#define MFMA_Q(q)                                                                   \
    __builtin_amdgcn_s_setprio(1);                                                  \
    _Pragma("unroll")                                                               \
    for (int e = 0; e < 2; e++)                                                     \
      _Pragma("unroll")                                                             \
      for (int ni = 0; ni < NFR; ni++) {                                            \
        acc[(q)*2+e][ni] = __builtin_amdgcn_mfma_f32_16x16x32_f16(af[q][e][0], bfr[ni][0], acc[(q)*2+e][ni], 0, 0, 0); \
        acc[(q)*2+e][ni] = __builtin_amdgcn_mfma_f32_16x16x32_f16(af[q][e][1], bfr[ni][1], acc[(q)*2+e][ni], 0, 0, 0); \
      }                                                                             \
    __builtin_amdgcn_s_setprio(0);

#define VMCNT_P()                                                                   \
    if constexpr (MODE == 0) { asm volatile("s_waitcnt vmcnt(7)" ::: "memory"); }   \
    else                     { asm volatile("s_waitcnt vmcnt(6)" ::: "memory"); }   \
    __builtin_amdgcn_sched_barrier(0);

  // prologue: T0 -> buf0, T1 -> buf1; wait T0 (T1 keeps flying); first frag reads
  stageAll(0, 0);
  stageAll(1, 1);
  VMCNT_P();
  SBAR();
  READ_BFR(0); READ_AF(0, 0);

#pragma unroll 1
  for (int it = 0; it < NITER; ++it) {
    int t2 = (2 * it + 2 < NT) ? 2 * it + 2 : NT - 1;   // clamped tail restage: harmless
    int t3 = (2 * it + 3 < NT) ? 2 * it + 3 : NT - 1;

    // ---- tile 2it (buf0) ----
    MFMA_Q(0); READ_AF(0, 1);
    MFMA_Q(1); READ_AF(0, 2);
    MFMA_Q(2); READ_AF(0, 3);
    LGKM0();            // all my buf0 reads complete (operands in regs)
    VMCNT0();           // my t_odd stage (issued 1 tile ago) landed in buf1
    SBAR();             // => ALL waves' buf0 reads done + buf1 data visible
    stageAll(0, t2);    // overwrite buf0 (legal now)
    MFMA_Q(3);
    __builtin_amdgcn_sched_barrier(0);   // pin bfr reload after its last consumer
    READ_BFR(1); READ_AF(1, 0);

    // ---- tile 2it+1 (buf1) ----
    MFMA_Q(0); READ_AF(1, 1);
    MFMA_Q(1); READ_AF(1, 2);
    MFMA_Q(2); READ_AF(1, 3);
    LGKM0();
    VMCNT0();           // t2 stage landed in buf0
    SBAR();
    stageAll(1, t3);
    MFMA_Q(3);
    __builtin_amdgcn_sched_barrier(0);
    READ_BFR(0); READ_AF(0, 0);
  }
  asm volatile("s_waitcnt vmcnt(0) lgkmcnt(0)" ::: "memory");  // drain tail ops

  // epilogue: C layout col = l&15, row = (l>>4)*4 + r
#pragma unroll
  for (int mi = 0; mi < 8; mi++) {
    int gm = m0 + wm * 128 + mi * 16 + (hi << 2);
#pragma unroll
    for (int ni = 0; ni < NFR; ni++) {
      int gn = n0 + wn * WN + ni * 16 + lo;
      if (MODE == 0) {
        int proj = gn >> 11, nn = gn & 2047;
        const float* bp = (proj == 0) ? b0 : (proj == 1) ? b1 : b2;
        float bias = bp[nn];
        int h = nn >> 7, d = nn & 127;
        int b = gm >> 11;
        int t0 = gm & 2047;
        if (proj < 2) {
#pragma unroll
          for (int r = 0; r < 4; r++) {
            Oh[(size_t)proj * ((size_t)NB * NH * TSEQ * DKH) +
               (((size_t)(b * NH + h) * TSEQ + t0 + r) * DKH) + d] = (f16)(acc[mi][ni][r] + bias);
          }
        } else {
          // V^T: [B,H,Dk,T] -- 4 consecutive t -> packed 8B store
          f16x4 pk;
#pragma unroll
          for (int r = 0; r < 4; r++) pk[r] = (f16)(acc[mi][ni][r] + bias);
          *(f16x4*)(Oh + 2ull * ((size_t)NB * NH * TSEQ * DKH) +
                    ((size_t)(b * NH + h) * DKH + d) * TSEQ + t0) = pk;
        }
      } else {
        float bias = b0[gn];
#pragma unroll
        for (int r = 0; r < 4; r++)
          Of[(size_t)(gm + r) * DM + gn] = acc[mi][ni][r] + bias;
      }
    }
  }
#undef READ_BFR
#undef READ_AF
#undef MFMA_Q
#undef VMCNT_P
}

// ---------------- flash attention v2 (swapped-QK^T, in-lane softmax) ----------------
__global__ __launch_bounds__(256, 2) void attn_kernel(const f16* __restrict__ Qb, const f16* __restrict__ Kb,
                                                      const f16* __restrict__ Vtb, f16* __restrict__ AO) {
  __shared__ f16 Ks[64 * 128];
  __shared__ f16 Vt[128 * 64];
  __shared__ f16 Ps[4][32 * 72];
  int tid = threadIdx.x, l = tid & 63, w = tid >> 6;
  int lo = l & 15, hi = l >> 4;
  int lin = blockIdx.x;
  int xcd = lin & 7, slot = lin >> 3;
  int bh = xcd * 4 + (slot & 3), qt = slot >> 2;   // bijective: 8 xcd * 4 bh * 16 qt
  const float CSC = 0.12753257f;   // (1/sqrt(128)) * log2(e)
  const float THR = 62.0f;         // raw-score defer threshold: p <= 2^(62*CSC) ~ 2^7.9
  const f16* Qg = Qb + (size_t)bh * TSEQ * DKH;
  const f16* Kg = Kb + (size_t)bh * TSEQ * DKH;
  const f16* Vg = Vtb + (size_t)bh * DKH * TSEQ;   // [Dk][T]

  // Q fragments in registers. As B-operand: col = lo = q-row, k(d) = c*32 + hi*8
  f16x8 aq[2][4];
#pragma unroll
  for (int hf = 0; hf < 2; hf++) {
    int qrow = qt * 128 + w * 32 + hf * 16 + lo;
#pragma unroll
    for (int c = 0; c < 4; c++)
      aq[hf][c] = *(const f16x8*)(Qg + (size_t)qrow * DKH + c * 32 + (hi << 3));
  }

  f32x4 o[2][8] = {};
  float mrow[2] = {-INFINITY, -INFINITY};
  float lrow[2] = {0.f, 0.f};

  for (int ktile = 0; ktile < TSEQ / 64; ++ktile) {
    __syncthreads();
    // stage K [64 kt][128 d]: 16 chunks/row, source chunk pre-swizzled by (row&15)
#pragma unroll
    for (int i = 0; i < 4; i++) {
      int chunk = (w * 4 + i) * 64 + l;
      int rowk = chunk >> 4, c = chunk & 15;
      int csw = c ^ (rowk & 15);
      gload_lds16(Kg + (size_t)(ktile * 64 + rowk) * DKH + csw * 8, &Ks[(w * 4 + i) * 512]);
    }
    // stage V^T [128 d][64 kt]: 8 chunks/row, source chunk pre-swizzled by (d&7)
#pragma unroll
    for (int i = 0; i < 4; i++) {
      int chunk = (w * 4 + i) * 64 + l;
      int d = chunk >> 3, c = chunk & 7;
      int csw = c ^ (d & 7);
      gload_lds16(Vg + (size_t)d * TSEQ + ktile * 64 + csw * 8, &Vt[(w * 4 + i) * 512]);
    }
    __syncthreads();

    // S^T = K Q^T: A = K rows (row=lo -> kt), B = Q (col=lo -> q).
    // Output: col = q = lo, row(reg r, hi) = kt = ks*16 + hi*4 + r.
    f32x4 s[2][4] = {};
    __builtin_amdgcn_s_setprio(1);
#pragma unroll
    for (int ks = 0; ks < 4; ++ks) {
      int ktl = ks * 16 + lo;
#pragma unroll
      for (int c = 0; c < 4; c++) {
        int cc = (c * 4 + hi) ^ lo;   // (ktl&15) == lo
        f16x8 bk = *(const f16x8*)&Ks[ktl * 128 + cc * 8];
        s[0][ks] = __builtin_amdgcn_mfma_f32_16x16x32_f16(bk, aq[0][c], s[0][ks], 0, 0, 0);
        s[1][ks] = __builtin_amdgcn_mfma_f32_16x16x32_f16(bk, aq[1][c], s[1][ks], 0, 0, 0);
      }
    }
    __builtin_amdgcn_s_setprio(0);

    // online softmax, reduction mostly in-lane (lane owns q-row = lo)
#pragma unroll
    for (int hf = 0; hf < 2; hf++) {
      float mk[4];
#pragma unroll
      for (int ks = 0; ks < 4; ks++)
        mk[ks] = fmaxf(fmaxf(s[hf][ks][0], s[hf][ks][1]), fmaxf(s[hf][ks][2], s[hf][ks][3]));
      float mt = fmaxf(fmaxf(mk[0], mk[1]), fmaxf(mk[2], mk[3]));
      mt = fmaxf(mt, __shfl_xor(mt, 16));
      mt = fmaxf(mt, __shfl_xor(mt, 32));   // row max, replicated across hi

      if (__any(mt > mrow[hf] + THR)) {     // wave-uniform; fires ~only on tile 0
        float mn = fmaxf(mrow[hf], mt);
        float al = exp2f((mrow[hf] - mn) * CSC);
        mrow[hf] = mn;
        lrow[hf] *= al;
        // redistribute al from lo-domain to o's (hi,r)-domain
        float alr[4];
#pragma unroll
        for (int r = 0; r < 4; r++) alr[r] = __shfl(al, (hi << 2) + r);
#pragma unroll
        for (int dsub = 0; dsub < 8; dsub++)
#pragma unroll
          for (int r = 0; r < 4; r++) o[hf][dsub][r] *= alr[r];
      }

      float mCn = -mrow[hf] * CSC;
      float sum = 0.f;
#pragma unroll
      for (int ks = 0; ks < 4; ks++) {
        f16x4 pk;
        float part = 0.f;
#pragma unroll
        for (int r = 0; r < 4; r++) {
          float p = exp2f(__builtin_fmaf(s[hf][ks][r], CSC, mCn));
          pk[r] = (f16)p;
          part += p;
        }
        sum += part;
        // P[q][kt]: row = hf*16+lo, col = ks*16 + hi*4 (+r packed) -> 8B store
        *(f16x4*)&Ps[w][(hf * 16 + lo) * 72 + ks * 16 + (hi << 2)] = pk;
      }
      sum += __shfl_xor(sum, 16);
      sum += __shfl_xor(sum, 32);
      lrow[hf] += sum;
    }

    // PV: o[hf][dsub] += P[16x64] * Vt^T[64 x dsub16]; each Vt read feeds 2 MFMAs
    f16x8 pa[2][2];
#pragma unroll
    for (int hf = 0; hf < 2; hf++)
#pragma unroll
      for (int kk = 0; kk < 2; kk++)
        pa[hf][kk] = *(const f16x8*)&Ps[w][(hf * 16 + lo) * 72 + kk * 32 + (hi << 3)];
    __builtin_amdgcn_s_setprio(1);
#pragma unroll
    for (int kk = 0; kk < 2; kk++) {
#pragma unroll
      for (int dsub = 0; dsub < 8; dsub++) {
        int d = dsub * 16 + lo;
        f16x8 vf = *(const f16x8*)&Vt[d * 64 + (((kk * 4 + hi) ^ (d & 7)) << 3)];
        o[0][dsub] = __builtin_amdgcn_mfma_f32_16x16x32_f16(pa[0][kk], vf, o[0][dsub], 0, 0, 0);
        o[1][dsub] = __builtin_amdgcn_mfma_f32_16x16x32_f16(pa[1][kk], vf, o[1][dsub], 0, 0, 0);
      }
    }
    __builtin_amdgcn_s_setprio(0);
  }

  // epilogue: AO[b][t][h*128 + d]; o row = q = hi*4+r, lrow lives in lo-domain
  int b = bh >> 4, h = bh & 15;
#pragma unroll
  for (int hf = 0; hf < 2; hf++) {
    float inv = 1.0f / lrow[hf];
    float invr[4];
#pragma unroll
    for (int r = 0; r < 4; r++) invr[r] = __shfl(inv, (hi << 2) + r);
#pragma unroll
    for (int r = 0; r < 4; r++) {
      int t = qt * 128 + w * 32 + hf * 16 + (hi << 2) + r;
      f16* dst = AO + ((size_t)b * TSEQ + t) * DM + h * DKH;
#pragma unroll
      for (int dsub = 0; dsub < 8; dsub++)
        dst[dsub * 16 + lo] = (f16)(o[hf][dsub][r] * invr[r]);
    }
  }
}

extern "C" void kernel_launch(void* const* d_in, const int* in_sizes, int n_in,
                              void* d_out, int out_size, void* d_ws, size_t ws_size,
                              hipStream_t stream) {
  const float* x  = (const float*)d_in[0];
  const float* Wq = (const float*)d_in[1];
  const float* bq = (const float*)d_in[2];
  const float* Wk = (const float*)d_in[3];
  const float* bk = (const float*)d_in[4];
  const float* Wv = (const float*)d_in[5];
  const float* bv = (const float*)d_in[6];
  const float* Wo = (const float*)d_in[7];
  const float* bo = (const float*)d_in[8];

  f16* ws    = (f16*)d_ws;
  f16* xb    = ws;                      //  8,388,608 elems  [reused as AO]
  f16* WtQKV = ws + 8388608ull;         // 12,582,912
  f16* WtO   = ws + 20971520ull;        //  4,194,304
  f16* Q     = ws + 25165824ull;        //  8,388,608
  f16* Kp    = ws + 33554432ull;        //  8,388,608
  f16* Vp    = ws + 41943040ull;        //  8,388,608  V^T [B,H,Dk,T]
  f16* AO    = xb;

  cvt_kernel<<<4096, 256, 0, stream>>>(x, xb, (NB * TSEQ * DM) / 8);
  wt_kernel<<<dim3(32, 32, 4), 256, 0, stream>>>(Wq, Wk, Wv, Wo, WtQKV, WtO);
  gemm_kernel<0><<<512, 512, 0, stream>>>(xb, WtQKV, bq, bk, bv, Q, nullptr);
  attn_kernel<<<512, 256, 0, stream>>>(Q, Kp, Vp, AO);
  gemm_kernel<1><<<256, 512, 0, stream>>>(AO, WtO, bo, nullptr, nullptr, nullptr, (float*)d_out);
}